// Round 16
// baseline (84.175 us; speedup 1.0000x reference)
//
#include <hip/hip_runtime.h>

#define IND 256
#define LDW 132   // LDS row stride (floats): 128 + 4 pad; 132%32=4 -> uniform banks; 528B%16=0 -> b128-aligned

__global__ __launch_bounds__(256, 4)
void FeatureEncodingLayer_30374008718005_kernel(
        const float* __restrict__ X,      // [1024][256]
        const float* __restrict__ W,      // [4096][256]
        const float* __restrict__ bias,   // [4096]
        float* __restrict__ outf)         // [1024][4][4][2048] float32 = Re(kron)
{
    // W tile [64 units][128 k] per phase, row-major so each lane streams ITS
    // unit's row with ds_read_b128 (4 k / 12 cyc). Single buffer, two phases,
    // 3 barriers total -- and NO barrier after any global store, so epilogue
    // stores drain async while other blocks compute (2 grid cohorts).
    __shared__ float Wsf[64 * LDW];      // 33,792 B -> 4 blocks/CU

    const int tid  = threadIdx.x;
    const int lane = tid & 63;
    const int wid  = __builtin_amdgcn_readfirstlane(tid >> 6);  // wave 0..3

    const int ut = blockIdx.x & 63;      // 64 unit tiles x 64 units
    const int bt = blockIdx.x >> 6;      // 32 batch tiles x 32 batches
    const int b0 = bt * 32;
    const int u0 = ut * 64;
    const int p0 = ut * 32;

    // staging roles: 4 threads per unit-row, 8 float4 each per phase
    const int su = tid >> 2;             // unit row 0..63
    const int ss = tid & 3;              // quad slot 0..3

    const float* xc = X + (size_t)(b0 + 8 * wid) * IND;   // wave-uniform -> s_load

    float acc[8];
#pragma unroll
    for (int i = 0; i < 8; ++i) acc[i] = 0.f;

#define STAGE(ph) do {                                                         \
    _Pragma("unroll")                                                          \
    for (int j = 0; j < 8; ++j) {                                              \
        const int kl = 4 * ss + 16 * j;                                        \
        const float4 v = *reinterpret_cast<const float4*>(                     \
            W + (size_t)(u0 + su) * IND + (ph) * 128 + kl);                    \
        *reinterpret_cast<float4*>(&Wsf[su * LDW + kl]) = v;                   \
    }                                                                          \
    } while (0)

#pragma unroll
    for (int ph = 0; ph < 2; ++ph) {
        if (ph) __syncthreads();         // all readers done with buffer
        STAGE(ph);
        __syncthreads();                 // buffer ready (drains stage loads only)

        // barrier-free K half: 32x (ds_read_b128 + 32 FMA)
#pragma unroll 4
        for (int k4 = 0; k4 < 32; ++k4) {
            const float4 wq = *reinterpret_cast<const float4*>(
                &Wsf[lane * LDW + k4 * 4]);
            const float wv[4] = {wq.x, wq.y, wq.z, wq.w};
            const int kbase = ph * 128 + k4 * 4;
#pragma unroll
            for (int kk = 0; kk < 4; ++kk) {
#pragma unroll
                for (int i = 0; i < 8; ++i)
                    acc[i] = fmaf(xc[i * IND + kbase + kk], wv[kk], acc[i]);
            }
        }
    }
#undef STAGE

    // ---- epilogue: lane owns unit u0+lane; pair partner via shfl_xor(1) ----
    const float bl  = bias[u0 + lane];
    const int   odd = lane & 1;

#pragma unroll
    for (int i = 0; i < 8; ++i) {
        const int b = b0 + 8 * wid + i;
        const float th = acc[i] + bl;
        float s_, c_;
        __sincosf(th, &s_, &c_);
        const float sp = __shfl_xor(s_, 1, 64);
        const float cp = __shfl_xor(c_, 1, 64);

        const float cA = odd ? cp : c_;      // even lane holds theta_A
        const float cB = odd ? c_ : cp;
        const float ca = 0.5f * (1.f + cA);  // cos^2(tA/2)
        const float sa = 0.5f * (1.f - cA);  // sin^2(tA/2)
        const float cb = 0.5f * (1.f + cB);
        const float sb = 0.5f * (1.f - cB);
        const float oo = 0.25f * s_ * sp;    // sin(tA)sin(tB)/4 (parity-symmetric)

        // nonzero slots: even {0,3,5,6}, odd {9,10,12,15}
        const int r0 = odd ? 9  : 0;  const float v0 = odd ?  oo      : ca * cb;
        const int r1 = odd ? 10 : 3;  const float v1 = odd ?  sa * cb : -oo;
        const int r2 = odd ? 12 : 5;  const float v2 = odd ? -oo      : ca * sb;
        const int r3 = odd ? 15 : 6;  const float v3 = odd ?  sa * sb : oo;
        // zero slots: even {1,2,4,7}, odd {8,11,13,14}
        const int z0 = odd ? 8  : 1;
        const int z1 = odd ? 11 : 2;
        const int z2 = odd ? 13 : 4;
        const int z3 = odd ? 14 : 7;

        float* bp = outf + (size_t)b * 32768 + p0 + (lane >> 1);
        bp[r0 * 2048] = v0;
        bp[r1 * 2048] = v1;
        bp[r2 * 2048] = v2;
        bp[r3 * 2048] = v3;
        bp[z0 * 2048] = 0.f;
        bp[z1 * 2048] = 0.f;
        bp[z2 * 2048] = 0.f;
        bp[z3 * 2048] = 0.f;
    }
}

extern "C" void kernel_launch(void* const* d_in, const int* in_sizes, int n_in,
                              void* d_out, int out_size, void* d_ws, size_t ws_size,
                              hipStream_t stream) {
    const float* X  = (const float*)d_in[0];
    const float* W  = (const float*)d_in[1];
    const float* bv = (const float*)d_in[2];

    // 32 batch-tiles x 64 unit-tiles = 2048 blocks; 4 blocks/CU resident
    // -> 2 cohorts, so cohort 1's store burst drains under cohort 2's compute.
    FeatureEncodingLayer_30374008718005_kernel<<<dim3(2048), dim3(256), 0, stream>>>(
        X, W, bv, (float*)d_out);
}

// Round 17
// 56.423 us; speedup vs baseline: 1.4919x; 1.4919x over previous
//
#include <hip/hip_runtime.h>

#define IND 256
#define KC  64   // k per chunk; 4 chunks

__global__ __launch_bounds__(256, 2)
void FeatureEncodingLayer_30374008718005_kernel(
        const float* __restrict__ X,      // [1024][256]
        const float* __restrict__ W,      // [4096][256]
        const float* __restrict__ bias,   // [4096]
        float* __restrict__ outf)         // [1024][4][4][2048] float32 = Re(kron)
{
    // Pair-interleaved, XOR-swizzled W tile: word (kp, u, k&1) lives at
    // Ws[buf][kp][(2u + (k&1)) ^ ((kp&7)<<2)].  A lane's ds_read_b128 at
    // col 4*lane^sw returns its unit-pair x 2 k's with 8x8 optimal banking.
    __shared__ float Ws[2][KC / 2][256];   // 64 KB -> 2 blocks/CU -> 2 cohorts

    const int tid  = threadIdx.x;
    const int lane = tid & 63;
    const int wid  = __builtin_amdgcn_readfirstlane(tid >> 6);  // wave 0..3

    const int ut = blockIdx.x & 31;    // 32 unit tiles x 128 units
    const int bt = blockIdx.x >> 5;    // 32 batch tiles x 32 batches
    const int b0 = bt * 32;
    const int u0 = ut * 128;
    const int p0 = ut * 64;

    // staging roles: 128 u x 64 k per chunk; 16 lanes cover one row's 256 B
    const int q  = tid & 15;           // k-quad: local k = 4q..4q+3
    const int rq = tid >> 4;           // row subgroup 0..15

    const float* xc = X + (size_t)(b0 + 8 * wid) * IND;   // wave-uniform -> s_load

    float acc[8][2];
#pragma unroll
    for (int i = 0; i < 8; ++i) { acc[i][0] = 0.f; acc[i][1] = 0.f; }

    float4 pf[8];
#define STAGE_LOAD(c) do {                                                     \
    _Pragma("unroll")                                                          \
    for (int j = 0; j < 8; ++j)                                                \
        pf[j] = *reinterpret_cast<const float4*>(                              \
            W + (size_t)(u0 + rq + 16 * j) * IND + (c) * KC + q * 4);          \
    } while (0)

    // float4 = unit u, local k 4q..4q+3 -> rows 2q (k&1=0,1), 2q+1 (k&1=0,1)
#define STAGE_WRITE(buf) do {                                                  \
    const int r0  = 2 * q, r1 = 2 * q + 1;                                     \
    const int sw0 = (r0 & 7) << 2, sw1 = (r1 & 7) << 2;                        \
    _Pragma("unroll")                                                          \
    for (int j = 0; j < 8; ++j) {                                              \
        const int u2 = 2 * (rq + 16 * j);                                      \
        *reinterpret_cast<float2*>(&Ws[buf][r0][u2 ^ sw0]) =                   \
            make_float2(pf[j].x, pf[j].y);                                     \
        *reinterpret_cast<float2*>(&Ws[buf][r1][u2 ^ sw1]) =                   \
            make_float2(pf[j].z, pf[j].w);                                     \
    }                                                                          \
    } while (0)

    STAGE_LOAD(0);
    STAGE_WRITE(0);
    __syncthreads();

    for (int c = 0; c < IND / KC; ++c) {
        const int cur = c & 1;
        if (c < IND / KC - 1) STAGE_LOAD(c + 1);   // prefetch, hidden by compute

#pragma unroll 8
        for (int kp = 0; kp < KC / 2; ++kp) {
            const int sw = (kp & 7) << 2;
            const float4 wq = *reinterpret_cast<const float4*>(
                &Ws[cur][kp][(4 * lane) ^ sw]);
            // wq = {W[2lane][2kp], W[2lane][2kp+1], W[2lane+1][2kp], W[2lane+1][2kp+1]}
            const int kg = c * KC + 2 * kp;
#pragma unroll
            for (int i = 0; i < 8; ++i) {
                const float x0 = xc[i * IND + kg];
                const float x1 = xc[i * IND + kg + 1];
                acc[i][0] = fmaf(x0, wq.x, acc[i][0]);
                acc[i][0] = fmaf(x1, wq.y, acc[i][0]);
                acc[i][1] = fmaf(x0, wq.z, acc[i][1]);
                acc[i][1] = fmaf(x1, wq.w, acc[i][1]);
            }
        }
        if (c < IND / KC - 1) {
            STAGE_WRITE(cur ^ 1);                  // waits only its own loads
            __syncthreads();                       // one barrier per chunk
        }
    }
#undef STAGE_LOAD
#undef STAGE_WRITE

    // ---- epilogue: lane owns pair p0+lane (units u0+2lane, +1), 8 batches ----
    const float2 bv = *reinterpret_cast<const float2*>(bias + u0 + 2 * lane);

#pragma unroll
    for (int i = 0; i < 8; ++i) {
        const int b = b0 + 8 * wid + i;
        const float tA = acc[i][0] + bv.x;
        const float tB = acc[i][1] + bv.y;
        float sA, cA, sB, cB;
        __sincosf(tA, &sA, &cA);
        __sincosf(tB, &sB, &cB);
        const float ca = 0.5f * (1.f + cA);   // cos^2(tA/2)
        const float sa = 0.5f * (1.f - cA);   // sin^2(tA/2)
        const float cb = 0.5f * (1.f + cB);
        const float sb = 0.5f * (1.f - cB);
        const float oo = 0.25f * sA * sB;     // sin(tA)/2 * sin(tB)/2

        float* bp = outf + (size_t)b * 32768 + p0 + lane;
        bp[ 0 * 2048] =  ca * cb;
        bp[ 1 * 2048] = 0.f;
        bp[ 2 * 2048] = 0.f;
        bp[ 3 * 2048] = -oo;
        bp[ 4 * 2048] = 0.f;
        bp[ 5 * 2048] =  ca * sb;
        bp[ 6 * 2048] =  oo;
        bp[ 7 * 2048] = 0.f;
        bp[ 8 * 2048] = 0.f;
        bp[ 9 * 2048] =  oo;
        bp[10 * 2048] =  sa * cb;
        bp[11 * 2048] = 0.f;
        bp[12 * 2048] = -oo;
        bp[13 * 2048] = 0.f;
        bp[14 * 2048] = 0.f;
        bp[15 * 2048] =  sa * sb;
    }
}

extern "C" void kernel_launch(void* const* d_in, const int* in_sizes, int n_in,
                              void* d_out, int out_size, void* d_ws, size_t ws_size,
                              hipStream_t stream) {
    const float* X  = (const float*)d_in[0];
    const float* W  = (const float*)d_in[1];
    const float* bv = (const float*)d_in[2];

    // 32 bt x 32 ut = 1024 blocks; 64 KB LDS -> 2 blocks/CU -> 512 resident
    // -> 2 cohorts: second cohort's compute overlaps first cohort's store drain.
    FeatureEncodingLayer_30374008718005_kernel<<<dim3(1024), dim3(256), 0, stream>>>(
        X, W, bv, (float*)d_out);
}